// Round 8
// baseline (178.613 us; speedup 1.0000x reference)
//
#include <hip/hip_runtime.h>

#define NB 32
#define N1 512
#define N2 512
#define DF 128
#define MW 256
#define KD 96
#define INVG 10.0f
#define GAM 0.1f
#define BARRIER 10000.0f

// ws layout (floats)
#define WS_NODE  0
#define WS_ABUF  (WS_NODE + NB*MW*KD)
#define WS_BBUF  (WS_ABUF + NB*MW*KD)

__device__ __forceinline__ bool feq(float a, float b) {
  return fabsf(a - b) <= 1e-4f * fmaxf(fabsf(a), fabsf(b)) + 1e-12f;
}

__device__ __forceinline__ float edgec(float s, float rdtv, float gub) {
  float d = s - 1.0f, ng = fminf(s, 0.f), ov = fmaxf(s - gub, 0.f);
  return rdtv*d*d + BARRIER*(ng*ng + ov*ov);
}

// ---------------- KA: fused rowmax + node costs ----------------
// grid (8 m-tiles, NB b), 256 threads.
__global__ __launch_bounds__(256) void k1_node(const float* __restrict__ s1f,
                                               const float* __restrict__ s2f,
                                               const float* __restrict__ tw,
                                               const float* __restrict__ glb_lb,
                                               const float* __restrict__ glb_ub,
                                               const float* __restrict__ t1,
                                               const float* __restrict__ t2,
                                               float* __restrict__ ws) {
  const int mb = blockIdx.x;
  const int b  = blockIdx.y;
  const int t  = threadIdx.x;
  const int lane = t & 63;
  const int wv = t >> 6;
  __shared__ float s1L[32*132];
  __shared__ float s2L[96*132];
  __shared__ float ndt[32*99];
  __shared__ float wtsL[32], lbL[32], ubL[32];
  __shared__ int   matchL[32];
  __shared__ float redm[8];

  // inline rowmax (was k0): T1 = max t1[b], T2 = max t2[b]
  {
    float m1 = -1e30f, m2 = -1e30f;
    for (int i = t; i < N1; i += 256) m1 = fmaxf(m1, t1[b*N1+i]);
    for (int i = t; i < N2; i += 256) m2 = fmaxf(m2, t2[b*N2+i]);
    #pragma unroll
    for (int o = 32; o; o >>= 1) {
      m1 = fmaxf(m1, __shfl_down(m1, o));
      m2 = fmaxf(m2, __shfl_down(m2, o));
    }
    if (lane == 0) { redm[wv] = m1; redm[4+wv] = m2; }
  }
  __syncthreads();
  const float T1 = fmaxf(fmaxf(redm[0], redm[1]), fmaxf(redm[2], redm[3]));
  const float T2 = fmaxf(fmaxf(redm[4], redm[5]), fmaxf(redm[6], redm[7]));
  const float lb0 = glb_lb[b*MW] * T2;
  const float ub0 = glb_ub[b*MW] * T2;
  float4* s1L4 = (float4*)s1L;
  float4* s2L4 = (float4*)s2L;
  const float4* s1f4 = (const float4*)(s1f + (size_t)b*N1*DF);
  const float4* s2f4 = (const float4*)(s2f + (size_t)b*N2*DF);

  {
    const int d32 = t & 31;
    const int k8  = t >> 5;
    for (int kk = 0; kk < 12; kk++) {
      int k = k8 + 8*kk;
      float tau = lb0 + (ub0 - lb0) * (float)k * (1.0f/95.0f);
      float x = fminf(fmaxf(tau / T2, 0.f), 1.f) * (float)(N2-1);
      int i0 = (int)x; i0 = max(0, min(i0, N2-2));
      float w = x - (float)i0;
      float4 f0 = s2f4[(size_t)i0*32 + d32];
      float4 f1 = s2f4[(size_t)(i0+1)*32 + d32];
      float4 r;
      r.x = f0.x + (f1.x - f0.x)*w; r.y = f0.y + (f1.y - f0.y)*w;
      r.z = f0.z + (f1.z - f0.z)*w; r.w = f0.w + (f1.w - f0.w)*w;
      s2L4[k*33 + d32] = r;
    }
  }
  {
    const int mi = t >> 3, q = t & 7;
    const int m = mb*32 + mi;
    float twm = tw[b*MW + m];
    float x = fminf(fmaxf(twm / T1, 0.f), 1.f) * (float)(N1-1);
    int i0 = (int)x; i0 = max(0, min(i0, N1-2));
    float w = x - (float)i0;
    #pragma unroll
    for (int j = 0; j < 4; j++) {
      int d4 = q + 8*j;
      float4 f0 = s1f4[(size_t)i0*32 + d4];
      float4 f1 = s1f4[(size_t)(i0+1)*32 + d4];
      float4 r;
      r.x = f0.x + (f1.x - f0.x)*w; r.y = f0.y + (f1.y - f0.y)*w;
      r.z = f0.z + (f1.z - f0.z)*w; r.w = f0.w + (f1.w - f0.w)*w;
      s1L4[mi*33 + d4] = r;
    }
  }
  if (t < 32) {
    int m = mb*32 + t, g = b*MW + m;
    float twm = tw[g];
    float prev = (m > 0) ? tw[g-1] : twm;
    float next = (m < MW-1) ? tw[g+1] : twm;
    wtsL[t] = 0.5f*(next - prev);
    float lbm = glb_lb[g]*T2, ubm = glb_ub[g]*T2;
    lbL[t] = lbm; ubL[t] = ubm;
    matchL[t] = (feq(lbm, lb0) && feq(ubm, ub0)) ? 1 : 0;
  }
  __syncthreads();

  const int mi = t >> 3, kg = t & 7;
  const int m = mb*32 + mi;
  float acc[12];
  #pragma unroll
  for (int i = 0; i < 12; i++) acc[i] = 0.f;
  if (matchL[mi]) {
    for (int d4 = 0; d4 < 32; d4++) {
      float4 s1v = s1L4[mi*33 + d4];
      #pragma unroll
      for (int k12 = 0; k12 < 12; k12++) {
        int k = kg + 8*k12;
        float4 s2v = s2L4[k*33 + d4];
        float dx = s1v.x - s2v.x, dy = s1v.y - s2v.y;
        float dz = s1v.z - s2v.z, dw = s1v.w - s2v.w;
        acc[k12] += dx*dx + dy*dy + dz*dz + dw*dw;
      }
    }
  } else {
    const float lbm = lbL[mi], ubm = ubL[mi];
    int i0a[12]; float wa[12];
    #pragma unroll
    for (int k12 = 0; k12 < 12; k12++) {
      int k = kg + 8*k12;
      float tau = lbm + (ubm - lbm) * (float)k * (1.0f/95.0f);
      float x = fminf(fmaxf(tau / T2, 0.f), 1.f) * (float)(N2-1);
      int i0 = (int)x; i0 = max(0, min(i0, N2-2));
      i0a[k12] = i0; wa[k12] = x - (float)i0;
    }
    for (int d4 = 0; d4 < 32; d4++) {
      float4 s1v = s1L4[mi*33 + d4];
      #pragma unroll
      for (int k12 = 0; k12 < 12; k12++) {
        float4 f0 = s2f4[(size_t)i0a[k12]*32 + d4];
        float4 f1 = s2f4[(size_t)(i0a[k12]+1)*32 + d4];
        float w = wa[k12];
        float ax = f0.x + (f1.x - f0.x)*w, ay = f0.y + (f1.y - f0.y)*w;
        float az = f0.z + (f1.z - f0.z)*w, aw = f0.w + (f1.w - f0.w)*w;
        float dx = s1v.x - ax, dy = s1v.y - ay, dz = s1v.z - az, dw = s1v.w - aw;
        acc[k12] += dx*dx + dy*dy + dz*dz + dw*dw;
      }
    }
  }
  {
    const float wts = wtsL[mi];
    const float lbm = lbL[mi], ubm = ubL[mi];
    #pragma unroll
    for (int k12 = 0; k12 < 12; k12++) {
      int k = kg + 8*k12;
      float nodev = acc[k12] * wts;
      float tau = lbm + (ubm - lbm) * (float)k * (1.0f/95.0f);
      if (m == 0)    nodev += BARRIER * tau * tau;
      if (m == MW-1) { float dd = tau - T2; nodev += BARRIER * dd * dd; }
      ndt[mi*99 + k] = nodev;
    }
  }
  __syncthreads();
  float* nodeP = ws + WS_NODE + ((size_t)b*MW + mb*32)*KD;
  for (int idx = t; idx < 32*KD; idx += 256) {
    int mi2 = idx / KD, kv = idx - mi2*KD;
    nodeP[idx] = ndt[mi2*99 + kv];
  }
}

// ---------------- KB: fused DP + readout ----------------
// grid NB blocks x 128 threads. Fast path: prefix-sum DP straight from global
// (rigorously validated from the data); one softmax -> E[k]; 256 affine
// outputs. Generic fallback: stage node into LDS, run the validated
// sequential register DP, then in-block readout.
__global__ __launch_bounds__(128) void k2_out(const float* __restrict__ tw,
                                              const float* __restrict__ glb_lb,
                                              const float* __restrict__ glb_ub,
                                              const float* __restrict__ reg_wt,
                                              const float* __restrict__ gubp,
                                              const float* __restrict__ t2,
                                              float* __restrict__ ws,
                                              float* __restrict__ out) {
  const int b = blockIdx.x;
  const int t = threadIdx.x;
  const int wv = t >> 6;
  const int lane = t & 63;
  __shared__ float ndL[MW*KD];   // 96 KB (used only on fallback)
  __shared__ float ndmL[MW];
  __shared__ float lbw[MW], ubw[MW], twv[MW];
  __shared__ float mir[2][KD];
  __shared__ float sred[8];
  __shared__ int skey[2];

  // T2 = max t2[b]
  {
    float m2 = -1e30f;
    for (int i = t; i < N2; i += 128) m2 = fmaxf(m2, t2[b*N2+i]);
    #pragma unroll
    for (int o = 32; o; o >>= 1) m2 = fmaxf(m2, __shfl_down(m2, o));
    if (lane == 0) sred[4+wv] = m2;
  }
  __syncthreads();
  const float T2 = fmaxf(sred[4], sred[5]);
  for (int i = t; i < MW; i += 128) {
    lbw[i] = glb_lb[b*MW+i]*T2;
    ubw[i] = glb_ub[b*MW+i]*T2;
    twv[i] = tw[b*MW+i];
  }
  const float r = reg_wt[b];
  const float gub = gubp[b];
  const float* __restrict__ nodeP = ws + WS_NODE + (size_t)b*MW*KD;
  __syncthreads();

  // ---- rigor checks: grid uniform across m, edge-cost floors, dt sanity ----
  const float lb0 = lbw[0], ub0 = ubw[0];
  const float g = (ub0 - lb0) * (1.0f/95.0f);
  bool keyok = true;
  float minE1 = 3e38f, minE2 = 3e38f, maxRdt = 0.f;
  for (int i = t; i < MW; i += 128)
    keyok = keyok && (lbw[i] == lb0) && (ubw[i] == ub0);
  for (int i = t; i < MW-1; i += 128) {
    float dtv = twv[i+1] - twv[i];
    if (!(dtv > 0.f)) keyok = false;
    else {
      float rdtv = r * dtv, sl = g / dtv;
      minE1 = fminf(minE1, fminf(edgec(sl, rdtv, gub), edgec(-sl, rdtv, gub)));
      minE2 = fminf(minE2, fminf(edgec(2.f*sl, rdtv, gub), edgec(-2.f*sl, rdtv, gub)));
      maxRdt = fmaxf(maxRdt, rdtv);
    }
  }

  // ---- prefix-sum scan straight from global, self-consistent diff stat ----
  const bool actS = t < KD;
  const int k = actS ? t : (KD-1);
  const bool hasn = actS && (k < KD-1);
  float P = 0.f, P2 = 0.f, mx = 0.f;
  #pragma unroll 4
  for (int m = 0; m < MW; m++) {
    float a = nodeP[m*KD + k];          // coalesced 96-float rows
    float an = __shfl_down(a, 1);       // k+1 within wave
    if (k == 63) an = nodeP[m*KD + 64]; // cross-wave boundary (1 lane)
    float bq = hasn ? an : a;
    P += a; P2 += bq;
    mx = fmaxf(mx, fabsf(P - P2));
  }
  if (!actS) mx = 0.f;
  {
    float wmx = mx, wE1 = minE1, wE2 = minE2, wR = maxRdt;
    #pragma unroll
    for (int o = 32; o; o >>= 1) {
      wmx = fmaxf(wmx, __shfl_xor(wmx, o));
      wE1 = fminf(wE1, __shfl_xor(wE1, o));
      wE2 = fminf(wE2, __shfl_xor(wE2, o));
      wR  = fmaxf(wR,  __shfl_xor(wR,  o));
    }
    int ka = __all(keyok ? 1 : 0);
    if (lane == 0) {
      sred[wv*4+0] = wmx; sred[wv*4+1] = wE1;
      sred[wv*4+2] = wE2; sred[wv*4+3] = wR;
      skey[wv] = ka;
    }
  }
  __syncthreads();
  const float MX = fmaxf(sred[0], sred[4]);
  const float E1 = fminf(sred[1], sred[5]);
  const float E2 = fminf(sred[2], sred[6]);
  const float RD = fmaxf(sred[3], sred[7]);
  const bool ok = skey[0] && skey[1] &&
                  (2.0f*MX   <= E1 - RD - 3.0f) &&
                  (190.0f*MX <= E2 - RD - 3.0f);

  if (ok) {
    // ---- fast path: logits = P (m-independent) -> E[k] -> affine outputs ----
    __syncthreads();
    float s = actS ? P : 3e38f;
    float mnv = s;
    #pragma unroll
    for (int o = 32; o; o >>= 1) mnv = fminf(mnv, __shfl_xor(mnv, o));
    if (lane == 0) sred[wv] = mnv;
    __syncthreads();
    const float mn = fminf(sred[0], sred[1]);
    float w = actS ? __expf((mn - P) * INVG) : 0.f;
    float num = w * (float)k, den = w;
    #pragma unroll
    for (int o = 32; o; o >>= 1) {
      num += __shfl_xor(num, o);
      den += __shfl_xor(den, o);
    }
    if (lane == 0) { sred[2+4*wv] = num; sred[3+4*wv] = den; }
    __syncthreads();
    const float q = ((sred[2] + sred[6]) / (sred[3] + sred[7])) * (1.0f/95.0f);
    for (int m = t; m < MW; m += 128)
      out[b*MW + m] = lbw[m] + (ubw[m] - lbw[m]) * q;
    return;
  }

  // ---------- generic fallback: stage node to LDS + sequential DP ----------
  {
    const float4* np4 = (const float4*)nodeP;
    float4* nl4 = (float4*)ndL;
    #pragma unroll
    for (int it = 0; it < (MW*KD/4)/128; it++)
      nl4[t + 128*it] = np4[t + 128*it];
    __syncthreads();
    for (int i2 = t; i2 < MW; i2 += 128) {
      float mnv = 3e38f;
      for (int kk = 0; kk < KD; kk++) mnv = fminf(mnv, ndL[i2*KD + kk]);
      ndmL[i2] = mnv;
    }
    __syncthreads();

    const int dir = t >> 6;
    const bool act = lane < 48;
    const int k0i = 2*lane, k1i = 2*lane+1;
    const float frk0 = (float)k0i*(1.f/95.f), frk1 = (float)k1i*(1.f/95.f);
    float* __restrict__ outP = ws + (dir ? WS_BBUF : WS_ABUF) + (size_t)b*MW*KD;

    float a0 = 3e38f, a1 = 3e38f;
    {
      const int m0 = dir ? (MW-1) : 0;
      if (act) {
        a0 = ndL[m0*KD + k0i]; a1 = ndL[m0*KD + k1i];
        mir[dir][k0i] = a0; mir[dir][k1i] = a1;
        float2 o; o.x = dir ? 0.f : a0; o.y = dir ? 0.f : a1;
        *(float2*)&outP[(size_t)m0*KD + k0i] = o;
      }
    }
    float Blo;
    {
      float bl = act ? fminf(a0, a1) : 3e38f;
      #pragma unroll
      for (int o = 1; o < 64; o <<= 1) bl = fminf(bl, __shfl_xor(bl, o));
      Blo = bl;
    }
    float e00=3e38f,e0m=3e38f,e0p=3e38f,e10=3e38f,e1m=3e38f,e1p=3e38f;
    float eo0=3e38f, eo1=3e38f, eminmin=0.f;
    float cL1=__int_as_float(0x7fc00000), cU1=cL1, cL2=cL1, cU2=cL1, cdt=cL1;

    float pL1, pU1, pL2, pU2, pt1, pt2, pnd0=0.f, pnd1=0.f, pndm;
    {
      const int i0_ = dir ? (MW-2) : 0;
      pL1=lbw[i0_]; pU1=ubw[i0_]; pL2=lbw[i0_+1]; pU2=ubw[i0_+1];
      pt1=twv[i0_]; pt2=twv[i0_+1];
      const int mn_ = dir ? i0_ : (i0_+1);
      if (act) { float2 v = *(const float2*)&ndL[mn_*KD + k0i]; pnd0=v.x; pnd1=v.y; }
      pndm = ndmL[mn_];
    }

    for (int step = 0; step < MW-1; step++) {
      const float L1=pL1, U1=pU1, L2=pL2, U2=pU2;
      const float dt = pt2 - pt1;
      const float nd0=pnd0, nd1=pnd1, ndmn=pndm;
      {
        const int sn = (step+1 < MW-1) ? (step+1) : step;
        const int in_ = dir ? (MW-2-sn) : sn;
        pL1=lbw[in_]; pU1=ubw[in_]; pL2=lbw[in_+1]; pU2=ubw[in_+1];
        pt1=twv[in_]; pt2=twv[in_+1];
        const int mn_ = dir ? in_ : (in_+1);
        if (act) { float2 v = *(const float2*)&ndL[mn_*KD + k0i]; pnd0=v.x; pnd1=v.y; }
        pndm = ndmL[mn_];
      }
      const bool kc = !(feq(L1,cL1)&&feq(U1,cU1)&&feq(L2,cL2)&&feq(U2,cU2)&&feq(dt,cdt));
      if (kc) {
        cL1=L1; cU1=U1; cL2=L2; cU2=U2; cdt=dt;
        float bl = act ? fminf(mir[dir][k0i], mir[dir][k1i]) : 3e38f;
        #pragma unroll
        for (int o = 1; o < 64; o <<= 1) bl = fminf(bl, __shfl_xor(bl, o));
        Blo = bl;
        const float invdt = 1.f/dt, rdt = r*dt;
        const float my0 = dir ? (L1+(U1-L1)*frk0) : (L2+(U2-L2)*frk0);
        const float my1 = dir ? (L1+(U1-L1)*frk1) : (L2+(U2-L2)*frk1);
        e00=3e38f; e0m=3e38f; e0p=3e38f; e10=3e38f; e1m=3e38f; e1p=3e38f;
        eo0=3e38f; eo1=3e38f;
        float emn = 3e38f;
        for (int j = 0; j < KD; j++) {
          const float frj = (float)j*(1.f/95.f);
          const float oth = dir ? (L2+(U2-L2)*frj) : (L1+(U1-L1)*frj);
          const float sl0 = (dir ? (oth-my0) : (my0-oth))*invdt;
          const float sl1 = (dir ? (oth-my1) : (my1-oth))*invdt;
          float d0=sl0-1.f, g0=fminf(sl0,0.f), v0=fmaxf(sl0-gub,0.f);
          float ej0 = rdt*d0*d0 + BARRIER*(g0*g0+v0*v0);
          float d1=sl1-1.f, g1=fminf(sl1,0.f), v1=fmaxf(sl1-gub,0.f);
          float ej1 = rdt*d1*d1 + BARRIER*(g1*g1+v1*v1);
          emn = fminf(emn, fminf(ej0, ej1));
          if      (j == k0i-1) e0m = ej0;
          else if (j == k0i)   e00 = ej0;
          else if (j == k0i+1) e0p = ej0;
          else                 eo0 = fminf(eo0, ej0);
          if      (j == k1i-1) e1m = ej1;
          else if (j == k1i)   e10 = ej1;
          else if (j == k1i+1) e1p = ej1;
          else                 eo1 = fminf(eo1, ej1);
        }
        if (!act) emn = 3e38f;
        #pragma unroll
        for (int o = 1; o < 64; o <<= 1) emn = fminf(emn, __shfl_xor(emn, o));
        eminmin = emn;
      }
      const float a1p = __shfl_up(a1, 1);
      const float a0n = __shfl_down(a0, 1);
      const float x0m = fminf(a1p + e0m, 3e38f);
      const float x00 = fminf(a0  + e00, 3e38f);
      const float x0p = fminf(a1  + e0p, 3e38f);
      const float x1m = fminf(a0  + e1m, 3e38f);
      const float x10 = fminf(a1  + e10, 3e38f);
      const float x1p = fminf(a0n + e1p, 3e38f);
      float mn0 = fminf(fminf(x0m, x00), x0p);
      float mn1 = fminf(fminf(x1m, x10), x1p);
      float sum0 = __expf((mn0-x0m)*INVG) + __expf((mn0-x00)*INVG) + __expf((mn0-x0p)*INVG);
      float sum1 = __expf((mn1-x1m)*INVG) + __expf((mn1-x10)*INVG) + __expf((mn1-x1p)*INVG);
      const bool bad = act && ((Blo + eo0 - mn0 < 8.7f) || (Blo + eo1 - mn1 < 8.7f));
      if (__any((int)bad)) {
        const float invdt = 1.f/dt, rdt = r*dt;
        const float my0 = dir ? (L1+(U1-L1)*frk0) : (L2+(U2-L2)*frk0);
        const float my1 = dir ? (L1+(U1-L1)*frk1) : (L2+(U2-L2)*frk1);
        mn0 = 3e38f; mn1 = 3e38f;
        for (int j = 0; j < KD; j++) {
          const float sj = mir[dir][j];
          const float frj = (float)j*(1.f/95.f);
          const float oth = dir ? (L2+(U2-L2)*frj) : (L1+(U1-L1)*frj);
          const float sl0 = (dir ? (oth-my0) : (my0-oth))*invdt;
          const float sl1 = (dir ? (oth-my1) : (my1-oth))*invdt;
          float d0=sl0-1.f, g0=fminf(sl0,0.f), v0=fmaxf(sl0-gub,0.f);
          float ej0 = rdt*d0*d0 + BARRIER*(g0*g0+v0*v0);
          float d1=sl1-1.f, g1=fminf(sl1,0.f), v1=fmaxf(sl1-gub,0.f);
          float ej1 = rdt*d1*d1 + BARRIER*(g1*g1+v1*v1);
          mn0 = fminf(mn0, fminf(sj + ej0, 3e38f));
          mn1 = fminf(mn1, fminf(sj + ej1, 3e38f));
        }
        sum0 = 0.f; sum1 = 0.f;
        for (int j = 0; j < KD; j++) {
          const float sj = mir[dir][j];
          const float frj = (float)j*(1.f/95.f);
          const float oth = dir ? (L2+(U2-L2)*frj) : (L1+(U1-L1)*frj);
          const float sl0 = (dir ? (oth-my0) : (my0-oth))*invdt;
          const float sl1 = (dir ? (oth-my1) : (my1-oth))*invdt;
          float d0=sl0-1.f, g0=fminf(sl0,0.f), v0=fmaxf(sl0-gub,0.f);
          float ej0 = rdt*d0*d0 + BARRIER*(g0*g0+v0*v0);
          float d1=sl1-1.f, g1=fminf(sl1,0.f), v1=fmaxf(sl1-gub,0.f);
          float ej1 = rdt*d1*d1 + BARRIER*(g1*g1+v1*v1);
          sum0 += __expf((mn0 - fminf(sj + ej0, 3e38f))*INVG);
          sum1 += __expf((mn1 - fminf(sj + ej1, 3e38f))*INVG);
        }
      }
      const float sv0 = mn0 - GAM*__logf(sum0);
      const float sv1 = mn1 - GAM*__logf(sum1);
      const float na0 = nd0 + sv0, na1 = nd1 + sv1;
      const int ic = dir ? (MW-2-step) : step;
      const int mnode = dir ? ic : (ic+1);
      if (act) {
        mir[dir][k0i] = na0; mir[dir][k1i] = na1;
        float2 o; o.x = dir ? sv0 : na0; o.y = dir ? sv1 : na1;
        *(float2*)&outP[(size_t)mnode*KD + k0i] = o;
      }
      a0 = act ? na0 : 3e38f;
      a1 = act ? na1 : 3e38f;
      Blo += eminmin + ndmn - 0.4575f;
    }

    // in-block readout (fallback only)
    __threadfence_block();
    __syncthreads();
    const float* __restrict__ Ab = ws + WS_ABUF + (size_t)b*MW*KD;
    const float* __restrict__ Bb = ws + WS_BBUF + (size_t)b*MW*KD;
    for (int m = t; m < MW; m += 128) {
      float mnv = 3e38f;
      for (int kk = 0; kk < KD; kk++)
        mnv = fminf(mnv, Ab[(size_t)m*KD+kk] + Bb[(size_t)m*KD+kk]);
      float num = 0.f, den = 0.f;
      for (int kk = 0; kk < KD; kk++) {
        float s = Ab[(size_t)m*KD+kk] + Bb[(size_t)m*KD+kk];
        float w = __expf((mnv - s) * INVG);
        num += w * (float)kk; den += w;
      }
      out[b*MW + m] = lbw[m] + (ubw[m] - lbw[m]) * (num/den) * (1.0f/95.0f);
    }
  }
}

extern "C" void kernel_launch(void* const* d_in, const int* in_sizes, int n_in,
                              void* d_out, int out_size, void* d_ws, size_t ws_size,
                              hipStream_t stream) {
  const float* s1f    = (const float*)d_in[0];
  const float* s2f    = (const float*)d_in[1];
  const float* regw   = (const float*)d_in[2];
  const float* glb_lb = (const float*)d_in[3];
  const float* glb_ub = (const float*)d_in[4];
  const float* gubp   = (const float*)d_in[5];
  const float* t1     = (const float*)d_in[6];
  const float* t2     = (const float*)d_in[7];
  const float* twp    = (const float*)d_in[8];
  float* ws  = (float*)d_ws;
  float* out = (float*)d_out;

  dim3 g1(8, NB);
  k1_node<<<g1, 256, 0, stream>>>(s1f, s2f, twp, glb_lb, glb_ub, t1, t2, ws);
  k2_out<<<NB, 128, 0, stream>>>(twp, glb_lb, glb_ub, regw, gubp, t2, ws, out);
}

// Round 9
// 111.443 us; speedup vs baseline: 1.6027x; 1.6027x over previous
//
#include <hip/hip_runtime.h>

#define NB 32
#define N1 512
#define N2 512
#define DF 128
#define MW 256
#define KD 96
#define INVG 10.0f
#define GAM 0.1f
#define BARRIER 10000.0f

// ws layout (floats)
#define WS_NODE  0
#define WS_ABUF  (WS_NODE + NB*MW*KD)
#define WS_BBUF  (WS_ABUF + NB*MW*KD)

__device__ __forceinline__ bool feq(float a, float b) {
  return fabsf(a - b) <= 1e-4f * fmaxf(fabsf(a), fabsf(b)) + 1e-12f;
}

__device__ __forceinline__ float edgec(float s, float rdtv, float gub) {
  float d = s - 1.0f, ng = fminf(s, 0.f), ov = fmaxf(s - gub, 0.f);
  return rdtv*d*d + BARRIER*(ng*ng + ov*ov);
}

// ---------------- KA: fused rowmax + node costs ----------------
// grid (8 m-tiles, NB b), 256 threads.
__global__ __launch_bounds__(256) void k1_node(const float* __restrict__ s1f,
                                               const float* __restrict__ s2f,
                                               const float* __restrict__ tw,
                                               const float* __restrict__ glb_lb,
                                               const float* __restrict__ glb_ub,
                                               const float* __restrict__ t1,
                                               const float* __restrict__ t2,
                                               float* __restrict__ ws) {
  const int mb = blockIdx.x;
  const int b  = blockIdx.y;
  const int t  = threadIdx.x;
  const int lane = t & 63;
  const int wv = t >> 6;
  __shared__ float s1L[32*132];
  __shared__ float s2L[96*132];
  __shared__ float ndt[32*99];
  __shared__ float wtsL[32], lbL[32], ubL[32];
  __shared__ int   matchL[32];
  __shared__ float redm[8];

  // inline rowmax: T1 = max t1[b], T2 = max t2[b]
  {
    float m1 = -1e30f, m2 = -1e30f;
    for (int i = t; i < N1; i += 256) m1 = fmaxf(m1, t1[b*N1+i]);
    for (int i = t; i < N2; i += 256) m2 = fmaxf(m2, t2[b*N2+i]);
    #pragma unroll
    for (int o = 32; o; o >>= 1) {
      m1 = fmaxf(m1, __shfl_down(m1, o));
      m2 = fmaxf(m2, __shfl_down(m2, o));
    }
    if (lane == 0) { redm[wv] = m1; redm[4+wv] = m2; }
  }
  __syncthreads();
  const float T1 = fmaxf(fmaxf(redm[0], redm[1]), fmaxf(redm[2], redm[3]));
  const float T2 = fmaxf(fmaxf(redm[4], redm[5]), fmaxf(redm[6], redm[7]));
  const float lb0 = glb_lb[b*MW] * T2;
  const float ub0 = glb_ub[b*MW] * T2;
  float4* s1L4 = (float4*)s1L;
  float4* s2L4 = (float4*)s2L;
  const float4* s1f4 = (const float4*)(s1f + (size_t)b*N1*DF);
  const float4* s2f4 = (const float4*)(s2f + (size_t)b*N2*DF);

  {
    const int d32 = t & 31;
    const int k8  = t >> 5;
    for (int kk = 0; kk < 12; kk++) {
      int k = k8 + 8*kk;
      float tau = lb0 + (ub0 - lb0) * (float)k * (1.0f/95.0f);
      float x = fminf(fmaxf(tau / T2, 0.f), 1.f) * (float)(N2-1);
      int i0 = (int)x; i0 = max(0, min(i0, N2-2));
      float w = x - (float)i0;
      float4 f0 = s2f4[(size_t)i0*32 + d32];
      float4 f1 = s2f4[(size_t)(i0+1)*32 + d32];
      float4 r;
      r.x = f0.x + (f1.x - f0.x)*w; r.y = f0.y + (f1.y - f0.y)*w;
      r.z = f0.z + (f1.z - f0.z)*w; r.w = f0.w + (f1.w - f0.w)*w;
      s2L4[k*33 + d32] = r;
    }
  }
  {
    const int mi = t >> 3, q = t & 7;
    const int m = mb*32 + mi;
    float twm = tw[b*MW + m];
    float x = fminf(fmaxf(twm / T1, 0.f), 1.f) * (float)(N1-1);
    int i0 = (int)x; i0 = max(0, min(i0, N1-2));
    float w = x - (float)i0;
    #pragma unroll
    for (int j = 0; j < 4; j++) {
      int d4 = q + 8*j;
      float4 f0 = s1f4[(size_t)i0*32 + d4];
      float4 f1 = s1f4[(size_t)(i0+1)*32 + d4];
      float4 r;
      r.x = f0.x + (f1.x - f0.x)*w; r.y = f0.y + (f1.y - f0.y)*w;
      r.z = f0.z + (f1.z - f0.z)*w; r.w = f0.w + (f1.w - f0.w)*w;
      s1L4[mi*33 + d4] = r;
    }
  }
  if (t < 32) {
    int m = mb*32 + t, g = b*MW + m;
    float twm = tw[g];
    float prev = (m > 0) ? tw[g-1] : twm;
    float next = (m < MW-1) ? tw[g+1] : twm;
    wtsL[t] = 0.5f*(next - prev);
    float lbm = glb_lb[g]*T2, ubm = glb_ub[g]*T2;
    lbL[t] = lbm; ubL[t] = ubm;
    matchL[t] = (feq(lbm, lb0) && feq(ubm, ub0)) ? 1 : 0;
  }
  __syncthreads();

  const int mi = t >> 3, kg = t & 7;
  const int m = mb*32 + mi;
  float acc[12];
  #pragma unroll
  for (int i = 0; i < 12; i++) acc[i] = 0.f;
  if (matchL[mi]) {
    for (int d4 = 0; d4 < 32; d4++) {
      float4 s1v = s1L4[mi*33 + d4];
      #pragma unroll
      for (int k12 = 0; k12 < 12; k12++) {
        int k = kg + 8*k12;
        float4 s2v = s2L4[k*33 + d4];
        float dx = s1v.x - s2v.x, dy = s1v.y - s2v.y;
        float dz = s1v.z - s2v.z, dw = s1v.w - s2v.w;
        acc[k12] += dx*dx + dy*dy + dz*dz + dw*dw;
      }
    }
  } else {
    const float lbm = lbL[mi], ubm = ubL[mi];
    int i0a[12]; float wa[12];
    #pragma unroll
    for (int k12 = 0; k12 < 12; k12++) {
      int k = kg + 8*k12;
      float tau = lbm + (ubm - lbm) * (float)k * (1.0f/95.0f);
      float x = fminf(fmaxf(tau / T2, 0.f), 1.f) * (float)(N2-1);
      int i0 = (int)x; i0 = max(0, min(i0, N2-2));
      i0a[k12] = i0; wa[k12] = x - (float)i0;
    }
    for (int d4 = 0; d4 < 32; d4++) {
      float4 s1v = s1L4[mi*33 + d4];
      #pragma unroll
      for (int k12 = 0; k12 < 12; k12++) {
        float4 f0 = s2f4[(size_t)i0a[k12]*32 + d4];
        float4 f1 = s2f4[(size_t)(i0a[k12]+1)*32 + d4];
        float w = wa[k12];
        float ax = f0.x + (f1.x - f0.x)*w, ay = f0.y + (f1.y - f0.y)*w;
        float az = f0.z + (f1.z - f0.z)*w, aw = f0.w + (f1.w - f0.w)*w;
        float dx = s1v.x - ax, dy = s1v.y - ay, dz = s1v.z - az, dw = s1v.w - aw;
        acc[k12] += dx*dx + dy*dy + dz*dz + dw*dw;
      }
    }
  }
  {
    const float wts = wtsL[mi];
    const float lbm = lbL[mi], ubm = ubL[mi];
    #pragma unroll
    for (int k12 = 0; k12 < 12; k12++) {
      int k = kg + 8*k12;
      float nodev = acc[k12] * wts;
      float tau = lbm + (ubm - lbm) * (float)k * (1.0f/95.0f);
      if (m == 0)    nodev += BARRIER * tau * tau;
      if (m == MW-1) { float dd = tau - T2; nodev += BARRIER * dd * dd; }
      ndt[mi*99 + k] = nodev;
    }
  }
  __syncthreads();
  float* nodeP = ws + WS_NODE + ((size_t)b*MW + mb*32)*KD;
  for (int idx = t; idx < 32*KD; idx += 256) {
    int mi2 = idx / KD, kv = idx - mi2*KD;
    nodeP[idx] = ndt[mi2*99 + kv];
  }
}

// ---------------- KB: fused DP + readout ----------------
// grid NB blocks x 128 threads. Node matrix bulk-staged to LDS with
// independent float4 loads (deep vmcnt pipeline — NOT a dependence-chained
// global scan; R8 showed direct-from-global scan is 10x slower). Fast path:
// prefix-sum DP from LDS -> one softmax -> 256 affine outputs. Generic
// fallback: validated sequential register DP + in-block readout.
__global__ __launch_bounds__(128) void k2_out(const float* __restrict__ tw,
                                              const float* __restrict__ glb_lb,
                                              const float* __restrict__ glb_ub,
                                              const float* __restrict__ reg_wt,
                                              const float* __restrict__ gubp,
                                              const float* __restrict__ t2,
                                              float* __restrict__ ws,
                                              float* __restrict__ out) {
  const int b = blockIdx.x;
  const int t = threadIdx.x;
  const int wv = t >> 6;
  const int lane = t & 63;
  __shared__ float ndL[MW*KD];   // 96 KB
  __shared__ float ndmL[MW];
  __shared__ float lbw[MW], ubw[MW], twv[MW];
  __shared__ float mir[2][KD];
  __shared__ float sred[8];
  __shared__ int skey[2];
  const float* __restrict__ nodeP = ws + WS_NODE + (size_t)b*MW*KD;

  // stage node -> LDS (24 independent float4 loads per thread)
  {
    const float4* np4 = (const float4*)nodeP;
    float4* nl4 = (float4*)ndL;
    #pragma unroll
    for (int it = 0; it < (MW*KD/4)/128; it++)
      nl4[t + 128*it] = np4[t + 128*it];
  }
  // T2 = max t2[b]
  {
    float m2 = -1e30f;
    for (int i = t; i < N2; i += 128) m2 = fmaxf(m2, t2[b*N2+i]);
    #pragma unroll
    for (int o = 32; o; o >>= 1) m2 = fmaxf(m2, __shfl_down(m2, o));
    if (lane == 0) sred[4+wv] = m2;
  }
  __syncthreads();
  const float T2 = fmaxf(sred[4], sred[5]);
  for (int i = t; i < MW; i += 128) {
    lbw[i] = glb_lb[b*MW+i]*T2;
    ubw[i] = glb_ub[b*MW+i]*T2;
    twv[i] = tw[b*MW+i];
  }
  const float r = reg_wt[b];
  const float gub = gubp[b];
  __syncthreads();

  // ---- rigor checks: grid uniform across m, edge-cost floors, dt sanity ----
  const float lb0 = lbw[0], ub0 = ubw[0];
  const float g = (ub0 - lb0) * (1.0f/95.0f);
  bool keyok = true;
  float minE1 = 3e38f, minE2 = 3e38f, maxRdt = 0.f;
  for (int i = t; i < MW; i += 128)
    keyok = keyok && (lbw[i] == lb0) && (ubw[i] == ub0);
  for (int i = t; i < MW-1; i += 128) {
    float dtv = twv[i+1] - twv[i];
    if (!(dtv > 0.f)) keyok = false;
    else {
      float rdtv = r * dtv, sl = g / dtv;
      minE1 = fminf(minE1, fminf(edgec(sl, rdtv, gub), edgec(-sl, rdtv, gub)));
      minE2 = fminf(minE2, fminf(edgec(2.f*sl, rdtv, gub), edgec(-2.f*sl, rdtv, gub)));
      maxRdt = fmaxf(maxRdt, rdtv);
    }
  }

  // ---- prefix-sum scan from LDS, self-consistent adjacent-diff stat ----
  const bool actS = t < KD;
  const int k = actS ? t : (KD-1);
  const bool hasn = actS && (k < KD-1);
  float P = 0.f, P2 = 0.f, mx = 0.f;
  #pragma unroll 8
  for (int m = 0; m < MW; m++) {
    float a  = ndL[m*KD + k];
    float bq = hasn ? ndL[m*KD + k + 1] : a;
    P += a; P2 += bq;
    mx = fmaxf(mx, fabsf(P - P2));
  }
  if (!actS) mx = 0.f;
  {
    float wmx = mx, wE1 = minE1, wE2 = minE2, wR = maxRdt;
    #pragma unroll
    for (int o = 32; o; o >>= 1) {
      wmx = fmaxf(wmx, __shfl_xor(wmx, o));
      wE1 = fminf(wE1, __shfl_xor(wE1, o));
      wE2 = fminf(wE2, __shfl_xor(wE2, o));
      wR  = fmaxf(wR,  __shfl_xor(wR,  o));
    }
    int ka = __all(keyok ? 1 : 0);
    if (lane == 0) {
      sred[wv*4+0] = wmx; sred[wv*4+1] = wE1;
      sred[wv*4+2] = wE2; sred[wv*4+3] = wR;
      skey[wv] = ka;
    }
  }
  __syncthreads();
  const float MX = fmaxf(sred[0], sred[4]);
  const float E1 = fminf(sred[1], sred[5]);
  const float E2 = fminf(sred[2], sred[6]);
  const float RD = fmaxf(sred[3], sred[7]);
  const bool ok = skey[0] && skey[1] &&
                  (2.0f*MX   <= E1 - RD - 3.0f) &&
                  (190.0f*MX <= E2 - RD - 3.0f);

  if (ok) {
    // ---- fast path: logits = P (m-independent) -> E[k] -> affine outputs ----
    __syncthreads();
    float s = actS ? P : 3e38f;
    float mnv = s;
    #pragma unroll
    for (int o = 32; o; o >>= 1) mnv = fminf(mnv, __shfl_xor(mnv, o));
    if (lane == 0) sred[wv] = mnv;
    __syncthreads();
    const float mn = fminf(sred[0], sred[1]);
    float w = actS ? __expf((mn - P) * INVG) : 0.f;
    float num = w * (float)k, den = w;
    #pragma unroll
    for (int o = 32; o; o >>= 1) {
      num += __shfl_xor(num, o);
      den += __shfl_xor(den, o);
    }
    if (lane == 0) { sred[2+4*wv] = num; sred[3+4*wv] = den; }
    __syncthreads();
    const float q = ((sred[2] + sred[6]) / (sred[3] + sred[7])) * (1.0f/95.0f);
    for (int m = t; m < MW; m += 128)
      out[b*MW + m] = lbw[m] + (ubw[m] - lbw[m]) * q;
    return;
  }

  // ---------- generic fallback: sequential register DP (ndL already staged) ----------
  {
    for (int i2 = t; i2 < MW; i2 += 128) {
      float mnv = 3e38f;
      for (int kk = 0; kk < KD; kk++) mnv = fminf(mnv, ndL[i2*KD + kk]);
      ndmL[i2] = mnv;
    }
    __syncthreads();

    const int dir = t >> 6;
    const bool act = lane < 48;
    const int k0i = 2*lane, k1i = 2*lane+1;
    const float frk0 = (float)k0i*(1.f/95.f), frk1 = (float)k1i*(1.f/95.f);
    float* __restrict__ outP = ws + (dir ? WS_BBUF : WS_ABUF) + (size_t)b*MW*KD;

    float a0 = 3e38f, a1 = 3e38f;
    {
      const int m0 = dir ? (MW-1) : 0;
      if (act) {
        a0 = ndL[m0*KD + k0i]; a1 = ndL[m0*KD + k1i];
        mir[dir][k0i] = a0; mir[dir][k1i] = a1;
        float2 o; o.x = dir ? 0.f : a0; o.y = dir ? 0.f : a1;
        *(float2*)&outP[(size_t)m0*KD + k0i] = o;
      }
    }
    float Blo;
    {
      float bl = act ? fminf(a0, a1) : 3e38f;
      #pragma unroll
      for (int o = 1; o < 64; o <<= 1) bl = fminf(bl, __shfl_xor(bl, o));
      Blo = bl;
    }
    float e00=3e38f,e0m=3e38f,e0p=3e38f,e10=3e38f,e1m=3e38f,e1p=3e38f;
    float eo0=3e38f, eo1=3e38f, eminmin=0.f;
    float cL1=__int_as_float(0x7fc00000), cU1=cL1, cL2=cL1, cU2=cL1, cdt=cL1;

    float pL1, pU1, pL2, pU2, pt1, pt2, pnd0=0.f, pnd1=0.f, pndm;
    {
      const int i0_ = dir ? (MW-2) : 0;
      pL1=lbw[i0_]; pU1=ubw[i0_]; pL2=lbw[i0_+1]; pU2=ubw[i0_+1];
      pt1=twv[i0_]; pt2=twv[i0_+1];
      const int mn_ = dir ? i0_ : (i0_+1);
      if (act) { float2 v = *(const float2*)&ndL[mn_*KD + k0i]; pnd0=v.x; pnd1=v.y; }
      pndm = ndmL[mn_];
    }

    for (int step = 0; step < MW-1; step++) {
      const float L1=pL1, U1=pU1, L2=pL2, U2=pU2;
      const float dt = pt2 - pt1;
      const float nd0=pnd0, nd1=pnd1, ndmn=pndm;
      {
        const int sn = (step+1 < MW-1) ? (step+1) : step;
        const int in_ = dir ? (MW-2-sn) : sn;
        pL1=lbw[in_]; pU1=ubw[in_]; pL2=lbw[in_+1]; pU2=ubw[in_+1];
        pt1=twv[in_]; pt2=twv[in_+1];
        const int mn_ = dir ? in_ : (in_+1);
        if (act) { float2 v = *(const float2*)&ndL[mn_*KD + k0i]; pnd0=v.x; pnd1=v.y; }
        pndm = ndmL[mn_];
      }
      const bool kc = !(feq(L1,cL1)&&feq(U1,cU1)&&feq(L2,cL2)&&feq(U2,cU2)&&feq(dt,cdt));
      if (kc) {
        cL1=L1; cU1=U1; cL2=L2; cU2=U2; cdt=dt;
        float bl = act ? fminf(mir[dir][k0i], mir[dir][k1i]) : 3e38f;
        #pragma unroll
        for (int o = 1; o < 64; o <<= 1) bl = fminf(bl, __shfl_xor(bl, o));
        Blo = bl;
        const float invdt = 1.f/dt, rdt = r*dt;
        const float my0 = dir ? (L1+(U1-L1)*frk0) : (L2+(U2-L2)*frk0);
        const float my1 = dir ? (L1+(U1-L1)*frk1) : (L2+(U2-L2)*frk1);
        e00=3e38f; e0m=3e38f; e0p=3e38f; e10=3e38f; e1m=3e38f; e1p=3e38f;
        eo0=3e38f; eo1=3e38f;
        float emn = 3e38f;
        for (int j = 0; j < KD; j++) {
          const float frj = (float)j*(1.f/95.f);
          const float oth = dir ? (L2+(U2-L2)*frj) : (L1+(U1-L1)*frj);
          const float sl0 = (dir ? (oth-my0) : (my0-oth))*invdt;
          const float sl1 = (dir ? (oth-my1) : (my1-oth))*invdt;
          float d0=sl0-1.f, g0=fminf(sl0,0.f), v0=fmaxf(sl0-gub,0.f);
          float ej0 = rdt*d0*d0 + BARRIER*(g0*g0+v0*v0);
          float d1=sl1-1.f, g1=fminf(sl1,0.f), v1=fmaxf(sl1-gub,0.f);
          float ej1 = rdt*d1*d1 + BARRIER*(g1*g1+v1*v1);
          emn = fminf(emn, fminf(ej0, ej1));
          if      (j == k0i-1) e0m = ej0;
          else if (j == k0i)   e00 = ej0;
          else if (j == k0i+1) e0p = ej0;
          else                 eo0 = fminf(eo0, ej0);
          if      (j == k1i-1) e1m = ej1;
          else if (j == k1i)   e10 = ej1;
          else if (j == k1i+1) e1p = ej1;
          else                 eo1 = fminf(eo1, ej1);
        }
        if (!act) emn = 3e38f;
        #pragma unroll
        for (int o = 1; o < 64; o <<= 1) emn = fminf(emn, __shfl_xor(emn, o));
        eminmin = emn;
      }
      const float a1p = __shfl_up(a1, 1);
      const float a0n = __shfl_down(a0, 1);
      const float x0m = fminf(a1p + e0m, 3e38f);
      const float x00 = fminf(a0  + e00, 3e38f);
      const float x0p = fminf(a1  + e0p, 3e38f);
      const float x1m = fminf(a0  + e1m, 3e38f);
      const float x10 = fminf(a1  + e10, 3e38f);
      const float x1p = fminf(a0n + e1p, 3e38f);
      float mn0 = fminf(fminf(x0m, x00), x0p);
      float mn1 = fminf(fminf(x1m, x10), x1p);
      float sum0 = __expf((mn0-x0m)*INVG) + __expf((mn0-x00)*INVG) + __expf((mn0-x0p)*INVG);
      float sum1 = __expf((mn1-x1m)*INVG) + __expf((mn1-x10)*INVG) + __expf((mn1-x1p)*INVG);
      const bool bad = act && ((Blo + eo0 - mn0 < 8.7f) || (Blo + eo1 - mn1 < 8.7f));
      if (__any((int)bad)) {
        const float invdt = 1.f/dt, rdt = r*dt;
        const float my0 = dir ? (L1+(U1-L1)*frk0) : (L2+(U2-L2)*frk0);
        const float my1 = dir ? (L1+(U1-L1)*frk1) : (L2+(U2-L2)*frk1);
        mn0 = 3e38f; mn1 = 3e38f;
        for (int j = 0; j < KD; j++) {
          const float sj = mir[dir][j];
          const float frj = (float)j*(1.f/95.f);
          const float oth = dir ? (L2+(U2-L2)*frj) : (L1+(U1-L1)*frj);
          const float sl0 = (dir ? (oth-my0) : (my0-oth))*invdt;
          const float sl1 = (dir ? (oth-my1) : (my1-oth))*invdt;
          float d0=sl0-1.f, g0=fminf(sl0,0.f), v0=fmaxf(sl0-gub,0.f);
          float ej0 = rdt*d0*d0 + BARRIER*(g0*g0+v0*v0);
          float d1=sl1-1.f, g1=fminf(sl1,0.f), v1=fmaxf(sl1-gub,0.f);
          float ej1 = rdt*d1*d1 + BARRIER*(g1*g1+v1*v1);
          mn0 = fminf(mn0, fminf(sj + ej0, 3e38f));
          mn1 = fminf(mn1, fminf(sj + ej1, 3e38f));
        }
        sum0 = 0.f; sum1 = 0.f;
        for (int j = 0; j < KD; j++) {
          const float sj = mir[dir][j];
          const float frj = (float)j*(1.f/95.f);
          const float oth = dir ? (L2+(U2-L2)*frj) : (L1+(U1-L1)*frj);
          const float sl0 = (dir ? (oth-my0) : (my0-oth))*invdt;
          const float sl1 = (dir ? (oth-my1) : (my1-oth))*invdt;
          float d0=sl0-1.f, g0=fminf(sl0,0.f), v0=fmaxf(sl0-gub,0.f);
          float ej0 = rdt*d0*d0 + BARRIER*(g0*g0+v0*v0);
          float d1=sl1-1.f, g1=fminf(sl1,0.f), v1=fmaxf(sl1-gub,0.f);
          float ej1 = rdt*d1*d1 + BARRIER*(g1*g1+v1*v1);
          sum0 += __expf((mn0 - fminf(sj + ej0, 3e38f))*INVG);
          sum1 += __expf((mn1 - fminf(sj + ej1, 3e38f))*INVG);
        }
      }
      const float sv0 = mn0 - GAM*__logf(sum0);
      const float sv1 = mn1 - GAM*__logf(sum1);
      const float na0 = nd0 + sv0, na1 = nd1 + sv1;
      const int ic = dir ? (MW-2-step) : step;
      const int mnode = dir ? ic : (ic+1);
      if (act) {
        mir[dir][k0i] = na0; mir[dir][k1i] = na1;
        float2 o; o.x = dir ? sv0 : na0; o.y = dir ? sv1 : na1;
        *(float2*)&outP[(size_t)mnode*KD + k0i] = o;
      }
      a0 = act ? na0 : 3e38f;
      a1 = act ? na1 : 3e38f;
      Blo += eminmin + ndmn - 0.4575f;
    }

    // in-block readout (fallback only)
    __threadfence_block();
    __syncthreads();
    const float* __restrict__ Ab = ws + WS_ABUF + (size_t)b*MW*KD;
    const float* __restrict__ Bb = ws + WS_BBUF + (size_t)b*MW*KD;
    for (int m = t; m < MW; m += 128) {
      float mnv = 3e38f;
      for (int kk = 0; kk < KD; kk++)
        mnv = fminf(mnv, Ab[(size_t)m*KD+kk] + Bb[(size_t)m*KD+kk]);
      float num = 0.f, den = 0.f;
      for (int kk = 0; kk < KD; kk++) {
        float s = Ab[(size_t)m*KD+kk] + Bb[(size_t)m*KD+kk];
        float w = __expf((mnv - s) * INVG);
        num += w * (float)kk; den += w;
      }
      out[b*MW + m] = lbw[m] + (ubw[m] - lbw[m]) * (num/den) * (1.0f/95.0f);
    }
  }
}

extern "C" void kernel_launch(void* const* d_in, const int* in_sizes, int n_in,
                              void* d_out, int out_size, void* d_ws, size_t ws_size,
                              hipStream_t stream) {
  const float* s1f    = (const float*)d_in[0];
  const float* s2f    = (const float*)d_in[1];
  const float* regw   = (const float*)d_in[2];
  const float* glb_lb = (const float*)d_in[3];
  const float* glb_ub = (const float*)d_in[4];
  const float* gubp   = (const float*)d_in[5];
  const float* t1     = (const float*)d_in[6];
  const float* t2     = (const float*)d_in[7];
  const float* twp    = (const float*)d_in[8];
  float* ws  = (float*)d_ws;
  float* out = (float*)d_out;

  dim3 g1(8, NB);
  k1_node<<<g1, 256, 0, stream>>>(s1f, s2f, twp, glb_lb, glb_ub, t1, t2, ws);
  k2_out<<<NB, 128, 0, stream>>>(twp, glb_lb, glb_ub, regw, gubp, t2, ws, out);
}